// Round 1
// 713.621 us; speedup vs baseline: 1.0795x; 1.0795x over previous
//
#include <hip/hip_runtime.h>

#define NN 2048
#define HH 256
#define RR 22
#define EE 20000

typedef unsigned short u16;
typedef unsigned int   u32;
typedef __bf16 bf16x8 __attribute__((ext_vector_type(8)));
typedef float  f32x16 __attribute__((ext_vector_type(16)));
typedef u16    u16x8  __attribute__((ext_vector_type(8)));

__device__ __forceinline__ u16 f2bf(float f){
  union{float f; u32 u;} v; v.f = f; u32 u = v.u;
  return (u16)((u + 0x7FFFu + ((u>>16)&1u)) >> 16);
}
__device__ __forceinline__ float bf2f(u16 v){
  union{u32 u; float f;} x; x.u = ((u32)v) << 16; return x.f;
}

// ---- CSR build ------------------------------------------------------------
__global__ void count_k(const int* __restrict__ ei, int* __restrict__ cnt){
  int idx = blockIdx.x*256 + threadIdx.x;
  if (idx >= RR*EE) return;
  int r = idx / EE, e = idx - r*EE;
  int dst = ei[(r*2+1)*EE + e];
  atomicAdd(&cnt[r*NN + dst], 1);
}

__global__ void scan_k(const int* __restrict__ cnt, int* __restrict__ offs,
                       int* __restrict__ cursor){
  int r = blockIdx.x, t = threadIdx.x;   // 22 blocks x 256 threads
  __shared__ int part[256];
  int base = r*NN;
  int loc[8]; int s = 0;
  #pragma unroll
  for (int u=0; u<8; u++){ loc[u] = cnt[base + t*8 + u]; s += loc[u]; }
  part[t] = s;
  __syncthreads();
  for (int off=1; off<256; off<<=1){
    int v = (t>=off) ? part[t-off] : 0;
    __syncthreads();
    part[t] += v;
    __syncthreads();
  }
  int run = r*EE + part[t] - s;
  #pragma unroll
  for (int u=0; u<8; u++){
    offs[base + t*8+u]   = run;
    cursor[base + t*8+u] = run;
    run += loc[u];
  }
}

__global__ void scatter_k(const int* __restrict__ ei, int* __restrict__ cursor,
                          int* __restrict__ csr){
  int idx = blockIdx.x*256 + threadIdx.x;
  if (idx >= RR*EE) return;
  int r = idx / EE, e = idx - r*EE;
  int src = ei[(r*2+0)*EE + e];
  int dst = ei[(r*2+1)*EE + e];
  int pos = atomicAdd(&cursor[r*NN + dst], 1);
  csr[pos] = src;
}

// ---- cast x0 fp32 -> bf16 (gather reads bf16: halves gather bytes) --------
__global__ void castx_k(const float* __restrict__ x0, u16* __restrict__ xb){
  int idx = blockIdx.x*256 + threadIdx.x;         // NN*HH/8 = 65536 threads
  const float4* p = (const float4*)x0 + (size_t)idx*2;
  float4 a = p[0], b = p[1];
  u16x8 st;
  st[0]=f2bf(a.x); st[1]=f2bf(a.y); st[2]=f2bf(a.z); st[3]=f2bf(a.w);
  st[4]=f2bf(b.x); st[5]=f2bf(b.y); st[6]=f2bf(b.z); st[7]=f2bf(b.w);
  ((u16x8*)xb)[idx] = st;
}

// ---- weights for BOTH layers in one pass ----------------------------------
// Bt2[l][p][o][i] bf16: p<22 = Wl[l][p]; p==22 = sum_r Wr[l][r]
// bias2[l][o] = sum_r bl[l][r][o]
__global__ void convW2_k(const float* __restrict__ Wl, const float* __restrict__ Wr,
                         const float* __restrict__ bl,
                         u16* __restrict__ Bt2, float* __restrict__ bias2){
  int idx = blockIdx.x*256 + threadIdx.x;   // 2*23*65536
  int l  = idx / (23*65536);
  int r2 = idx - l*(23*65536);
  int plane = r2 >> 16, rem = r2 & 65535;
  if (plane < RR){
    Bt2[idx] = f2bf(Wl[((size_t)l*RR + plane)*65536 + rem]);
  } else {
    float s = 0.f;
    for (int r=0;r<RR;r++) s += Wr[((size_t)l*RR + r)*65536 + rem];
    Bt2[idx] = f2bf(s);
  }
  if (plane == 0 && rem < HH){
    float b = 0.f;
    for (int r=0;r<RR;r++) b += bl[((size_t)l*RR + r)*HH + rem];
    bias2[l*HH + rem] = b;
  }
}

// ---- gather-mean into global bf16 G[p][n][h] ------------------------------
// grid (NN/32, RR), 256 threads. Each wave handles 8 rows as 4 pairs:
// half-wave (32 lanes x bf16x8 = 256 cols) per row -> 2 rows in flight,
// halving the serial edge-walk chain vs one-row-per-wave.
__global__ void __launch_bounds__(256) gather_k(
    const u16* __restrict__ xb, const int* __restrict__ offs,
    const int* __restrict__ cnt, const int* __restrict__ csr,
    u16* __restrict__ G)
{
  int p    = blockIdx.y;
  int m0   = blockIdx.x * 32;
  int wv   = threadIdx.x >> 6;
  int lane = threadIdx.x & 63;
  int half = lane >> 5;
  int c    = (lane & 31) * 8;          // bf16 col base, 16B load per lane

  for (int t = 0; t < 4; t++){
    int n   = m0 + wv*8 + t*2 + half;
    int off = offs[p*NN + n];
    int deg = cnt [p*NN + n];
    int dmax = max(deg, __shfl_xor(deg, 32));
    float a[8];
    #pragma unroll
    for (int u=0;u<8;u++) a[u] = 0.f;
    for (int e = 0; e < dmax; e++){
      if (e < deg){
        int s = csr[off + e];
        u16x8 v = *(const u16x8*)(xb + (size_t)s*HH + c);
        #pragma unroll
        for (int u=0;u<8;u++) a[u] += bf2f(v[u]);
      }
    }
    float inv = 1.0f / fmaxf((float)deg, 1.0f);
    u16x8 st;
    #pragma unroll
    for (int u=0;u<8;u++) st[u] = f2bf(a[u]*inv);
    *(u16x8*)(G + ((size_t)p*NN + n)*HH + c) = st;
  }
}

// ---- stacked-K GEMM, split-K over plane chunks ----------------------------
// grid (NN/32, 4): chunk y covers planes [6y, min(6y+6,23)); plane 22 = root (xb).
// No LDS: A/B bf16 frags straight from L1/L2-resident global. 256 blocks = 1/CU.
__global__ void __launch_bounds__(256) gemm_k(
    const u16* __restrict__ G, const u16* __restrict__ xb,
    const u16* __restrict__ Bt, float* __restrict__ Cp4)
{
  int m0   = blockIdx.x * 32;
  int y    = blockIdx.y;
  int wid  = threadIdx.x >> 6;
  int lane = threadIdx.x & 63;
  int colA  = wid*64 + (lane & 31);
  int colB  = colA + 32;
  int khalf = (lane >> 5) * 8;
  int arow  = lane & 31;

  f32x16 acc0, acc1;
  #pragma unroll
  for (int i=0;i<16;i++){ acc0[i]=0.f; acc1[i]=0.f; }

  int p0 = y*6, p1 = min(p0+6, 23);
  for (int p = p0; p < p1; p++){
    const u16* Ap = ((p < RR) ? (G + (size_t)p*NN*HH) : xb)
                    + (size_t)(m0 + arow)*HH + khalf;
    const u16* B0 = Bt + (size_t)p*65536 + (size_t)colA*HH + khalf;
    const u16* B1 = Bt + (size_t)p*65536 + (size_t)colB*HH + khalf;
    #pragma unroll
    for (int kk = 0; kk < HH; kk += 16){
      bf16x8 af = *(const bf16x8*)(Ap + kk);
      bf16x8 b0 = *(const bf16x8*)(B0 + kk);
      bf16x8 b1 = *(const bf16x8*)(B1 + kk);
      acc0 = __builtin_amdgcn_mfma_f32_32x32x16_bf16(af, b0, acc0, 0, 0, 0);
      acc1 = __builtin_amdgcn_mfma_f32_32x32x16_bf16(af, b1, acc1, 0, 0, 0);
    }
  }
  float* C = Cp4 + (size_t)y*NN*HH;
  #pragma unroll
  for (int reg=0; reg<16; reg++){
    int row = m0 + (reg&3) + 8*(reg>>2) + 4*(lane>>5);
    C[(size_t)row*HH + colA] = acc0[reg];
    C[(size_t)row*HH + colB] = acc1[reg];
  }
}

// ---- reduce 4 K-chunks + bias + relu -> x1 fp32 + xb bf16 -----------------
__global__ void reduce4_k(const float* __restrict__ Cp4, const float* __restrict__ bias,
                          float* __restrict__ x1, u16* __restrict__ xbo){
  int idx = blockIdx.x*256 + threadIdx.x;       // NN*HH/4 = 131072 threads
  float4 s = ((const float4*)Cp4)[idx];
  #pragma unroll
  for (int y=1; y<4; y++){
    float4 v = ((const float4*)(Cp4 + (size_t)y*NN*HH))[idx];
    s.x+=v.x; s.y+=v.y; s.z+=v.z; s.w+=v.w;
  }
  float4 b = ((const float4*)bias)[idx & 63];
  s.x = fmaxf(s.x + b.x, 0.f);
  s.y = fmaxf(s.y + b.y, 0.f);
  s.z = fmaxf(s.z + b.z, 0.f);
  s.w = fmaxf(s.w + b.w, 0.f);
  ((float4*)x1)[idx] = s;
  ushort4 st; st.x=f2bf(s.x); st.y=f2bf(s.y); st.z=f2bf(s.z); st.w=f2bf(s.w);
  ((ushort4*)xbo)[idx] = st;
}

// ---- coefficients: m[n][r], p[n][r] = m*a ---------------------------------
__global__ void coeff_k(const float* __restrict__ x2, const float* __restrict__ Wa,
                        const float* __restrict__ ba, const float* __restrict__ Wm,
                        const float* __restrict__ bm,
                        float* __restrict__ mbuf, float* __restrict__ pbuf){
  int idx = blockIdx.x*256 + threadIdx.x;   // NN*RR = 45056 exact
  int n = idx / RR, r = idx - n*RR;
  const float4* xr = (const float4*)(x2 + (size_t)n*HH);
  const float4* wa = (const float4*)(Wa + (size_t)r*HH);
  const float4* wm = (const float4*)(Wm + (size_t)r*HH);
  float da=0.f, dm=0.f;
  #pragma unroll 4
  for (int h=0; h<HH/4; h++){
    float4 xv = xr[h], av = wa[h], mv = wm[h];
    da += xv.x*av.x + xv.y*av.y + xv.z*av.z + xv.w*av.w;
    dm += xv.x*mv.x + xv.y*mv.y + xv.z*mv.z + xv.w*mv.w;
  }
  float a = fmaxf(da + ba[r], 0.f);
  float m = fmaxf(dm + bm[r], 0.f);
  mbuf[idx] = m;
  pbuf[idx] = m*a;
}

// ---- final: out[i,j] = sum_r m[i,r]*adj[i,j,r] + sum_r m[i,r]*a[i,r] ------
__global__ void final_k(const float* __restrict__ adj, const float* __restrict__ mbuf,
                        const float* __restrict__ pbuf, float* __restrict__ out){
  int i = blockIdx.y;
  int j = blockIdx.x*256 + threadIdx.x;
  float mv[RR];
  float s = 0.f;
  #pragma unroll
  for (int r=0;r<RR;r++){ mv[r] = mbuf[i*RR+r]; s += pbuf[i*RR+r]; }
  const float2* ap = (const float2*)(adj + ((size_t)i*NN + j)*RR);  // 88B row
  float acc = s;
  #pragma unroll
  for (int k=0;k<RR/2;k++){
    float2 w = ap[k];
    acc += mv[2*k]*w.x + mv[2*k+1]*w.y;
  }
  out[(size_t)i*NN + j] = acc;
}

extern "C" void kernel_launch(void* const* d_in, const int* in_sizes, int n_in,
                              void* d_out, int out_size, void* d_ws, size_t ws_size,
                              hipStream_t stream) {
  const float* x0  = (const float*)d_in[0];
  const float* adj = (const float*)d_in[1];
  const float* Wl  = (const float*)d_in[2];
  const float* bl  = (const float*)d_in[3];
  const float* Wr  = (const float*)d_in[4];
  const float* Wa  = (const float*)d_in[5];
  const float* ba  = (const float*)d_in[6];
  const float* Wm  = (const float*)d_in[7];
  const float* bm  = (const float*)d_in[8];
  const int*   ei  = (const int*)d_in[9];
  float* out = (float*)d_out;

  char* w = (char*)d_ws;
  auto alloc = [&](size_t bytes){ char* p = w; w += (bytes + 255) & ~255ull; return p; };
  int*   cnt    = (int*)  alloc((size_t)RR*NN*4);
  int*   offs   = (int*)  alloc((size_t)RR*NN*4);
  int*   cursor = (int*)  alloc((size_t)RR*NN*4);
  int*   csr    = (int*)  alloc((size_t)RR*EE*4);
  u16*   Bt2    = (u16*)  alloc((size_t)2*(RR+1)*HH*HH*2);
  float* bias2  = (float*)alloc((size_t)2*HH*4);
  u16*   G      = (u16*)  alloc((size_t)RR*NN*HH*2);   // 22 MB stacked-K bf16
  u16*   xb0    = (u16*)  alloc((size_t)NN*HH*2);
  u16*   xb1    = (u16*)  alloc((size_t)NN*HH*2);
  float* Cp4    = (float*)alloc((size_t)4*NN*HH*4);    // 8 MB split-K partials
  float* x1     = (float*)alloc((size_t)NN*HH*4);
  float* mbuf   = (float*)alloc((size_t)NN*RR*4);
  float* pbuf   = (float*)alloc((size_t)NN*RR*4);

  hipMemsetAsync(cnt, 0, (size_t)RR*NN*4, stream);
  count_k  <<<(RR*EE+255)/256, 256, 0, stream>>>(ei, cnt);
  scan_k   <<<RR, 256, 0, stream>>>(cnt, offs, cursor);
  scatter_k<<<(RR*EE+255)/256, 256, 0, stream>>>(ei, cursor, csr);
  castx_k  <<<(NN*HH/8)/256, 256, 0, stream>>>(x0, xb0);
  convW2_k <<<(2*(RR+1)*HH*HH)/256, 256, 0, stream>>>(Wl, Wr, bl, Bt2, bias2);

  // layer 0
  gather_k <<<dim3(NN/32, RR), 256, 0, stream>>>(xb0, offs, cnt, csr, G);
  gemm_k   <<<dim3(NN/32, 4), 256, 0, stream>>>(G, xb0, Bt2, Cp4);
  reduce4_k<<<(NN*HH/4)/256, 256, 0, stream>>>(Cp4, bias2, x1, xb1);
  // layer 1
  gather_k <<<dim3(NN/32, RR), 256, 0, stream>>>(xb1, offs, cnt, csr, G);
  gemm_k   <<<dim3(NN/32, 4), 256, 0, stream>>>(G, xb1, Bt2 + (size_t)(RR+1)*HH*HH, Cp4);
  reduce4_k<<<(NN*HH/4)/256, 256, 0, stream>>>(Cp4, bias2 + HH, x1, xb0);

  coeff_k<<<(NN*RR)/256, 256, 0, stream>>>(x1, Wa, ba, Wm, bm, mbuf, pbuf);
  final_k<<<dim3(NN/256, NN), 256, 0, stream>>>(adj, mbuf, pbuf, out);
}